// Round 1
// baseline (26.526 us; speedup 1.0000x reference)
//
#include <hip/hip_runtime.h>

// Problem constants from setup_inputs(): mixing (K=16, B=32, 1, W=256, H=256) f32.
#define K_ 16
#define B_ 32
#define W_ 256
#define H_ 256
#define KB_ (K_ * B_)
#define CHUNK_ (W_ * H_)   // 65536 elements per (k,b) slice

// One block per (k,b). 1024 threads, each reads 16 float4 (64 elems), tracks
// 4 integer maxima, block-reduces, thread 0 writes the 4 box scalars.
__global__ __launch_bounds__(1024) void box_from_mask_kernel(
    const float* __restrict__ mixing,
    const int* __restrict__ p_pad,
    const int* __restrict__ p_minb,
    const int* __restrict__ p_maxb,
    float* __restrict__ out)
{
    const int kb = blockIdx.x;        // k*B + b
    const int t  = threadIdx.x;       // 0..1023
    const float* base = mixing + (size_t)kb * CHUNK_;

    int mw = 0;    // max over masked elems of w
    int mWw = 0;   // max of (W - w)
    int mh = 0;    // max of h
    int mHh = 0;   // max of (H - h)

#pragma unroll
    for (int it = 0; it < 16; ++it) {
        const int idx = (it * 1024 + t) * 4;   // element offset within chunk
        const float4 v = *reinterpret_cast<const float4*>(base + idx);
        const int w = idx >> 8;                // idx / H
        const int h = idx & (H_ - 1);          // idx % H  (base h of the 4)
        const bool m0 = v.x > 0.5f;
        const bool m1 = v.y > 0.5f;
        const bool m2 = v.z > 0.5f;
        const bool m3 = v.w > 0.5f;
        if (m0 | m1 | m2 | m3) {
            mw  = max(mw,  w);
            mWw = max(mWw, W_ - w);
            const int hi = m3 ? 3 : (m2 ? 2 : (m1 ? 1 : 0)); // highest masked lane
            const int lo = m0 ? 0 : (m1 ? 1 : (m2 ? 2 : 3)); // lowest masked lane
            mh  = max(mh,  h + hi);
            mHh = max(mHh, H_ - (h + lo));
        }
    }

    // 64-lane wave reduction (wave = 64 on gfx950)
#pragma unroll
    for (int off = 32; off > 0; off >>= 1) {
        mw  = max(mw,  __shfl_xor(mw,  off));
        mWw = max(mWw, __shfl_xor(mWw, off));
        mh  = max(mh,  __shfl_xor(mh,  off));
        mHh = max(mHh, __shfl_xor(mHh, off));
    }

    __shared__ int s[4][16];   // 16 waves per block
    const int wave = t >> 6;
    const int lane = t & 63;
    if (lane == 0) {
        s[0][wave] = mw; s[1][wave] = mWw; s[2][wave] = mh; s[3][wave] = mHh;
    }
    __syncthreads();

    if (t == 0) {
        int a = 0, b = 0, c = 0, d = 0;
#pragma unroll
        for (int i = 0; i < 16; ++i) {
            a = max(a, s[0][i]);
            b = max(b, s[1][i]);
            c = max(c, s[2][i]);
            d = max(d, s[3][i]);
        }
        const float pad  = (float)(*p_pad);
        const float minb = (float)(*p_minb);
        const float maxb = (float)(*p_maxb);
        const float Wf = (float)W_, Hf = (float)H_;

        // ideal_x3 = a ; ideal_x1 = W - b ; ideal_y3 = c ; ideal_y1 = H - d
        const float x3 = fminf(fmaxf((float)a + pad,        0.0f), Wf);
        const float x1 = fminf(fmaxf((Wf - (float)b) - pad, 0.0f), Wf);
        const float y3 = fminf(fmaxf((float)c + pad,        0.0f), Hf);
        const float y1 = fminf(fmaxf((Hf - (float)d) - pad, 0.0f), Hf);

        out[0 * KB_ + kb] = 0.5f * (x1 + x3);
        out[1 * KB_ + kb] = 0.5f * (y1 + y3);
        out[2 * KB_ + kb] = fminf(fmaxf(x3 - x1, minb), maxb);
        out[3 * KB_ + kb] = fminf(fmaxf(y3 - y1, minb), maxb);
    }
}

extern "C" void kernel_launch(void* const* d_in, const int* in_sizes, int n_in,
                              void* d_out, int out_size, void* d_ws, size_t ws_size,
                              hipStream_t stream) {
    const float* mixing = (const float*)d_in[0];
    const int*   p_pad  = (const int*)d_in[1];
    const int*   p_minb = (const int*)d_in[2];
    const int*   p_maxb = (const int*)d_in[3];
    float* out = (float*)d_out;

    box_from_mask_kernel<<<dim3(KB_), dim3(1024), 0, stream>>>(
        mixing, p_pad, p_minb, p_maxb, out);
}